// Round 1
// baseline (1274.902 us; speedup 1.0000x reference)
//
#include <hip/hip_runtime.h>
#include <hip/hip_bf16.h>
#include <stdint.h>

// ---------------------------------------------------------------------------
// QuantLinearNet: y = fq8( fq8(x) @ fq4(W).T + bq )
// Key trick: quantized values are exact small integers -> do the matmul as a
// bf16 MFMA GEMM on the integer codes (exact: |acc| < 2^24), scale at the end.
// ---------------------------------------------------------------------------

typedef __attribute__((ext_vector_type(8))) short bf16x8;
typedef __attribute__((ext_vector_type(4))) float f32x4;

#define BM 128
#define BN 128
#define BK 64

__device__ __forceinline__ void async_copy16(const void* g, void* l) {
  __builtin_amdgcn_global_load_lds((const __attribute__((address_space(1))) void*)g,
                                   (__attribute__((address_space(3))) void*)l,
                                   16, 0, 0);
}

__device__ __forceinline__ float wave_max64(float v) {
#pragma unroll
  for (int off = 32; off > 0; off >>= 1) v = fmaxf(v, __shfl_xor(v, off, 64));
  return v;
}

__global__ void init_scal(unsigned* s) {
  if (threadIdx.x < 4) s[threadIdx.x] = 0u;
}

__global__ void maxabs4(const float4* __restrict__ x, int n4, unsigned* __restrict__ out) {
  float m = 0.f;
  for (int i = blockIdx.x * blockDim.x + threadIdx.x; i < n4; i += gridDim.x * blockDim.x) {
    float4 v = x[i];
    m = fmaxf(fmaxf(fabsf(v.x), fabsf(v.y)), fmaxf(fmaxf(fabsf(v.z), fabsf(v.w)), m));
  }
  m = wave_max64(m);
  __shared__ float wm[4];
  if ((threadIdx.x & 63) == 0) wm[threadIdx.x >> 6] = m;
  __syncthreads();
  if (threadIdx.x == 0)
    atomicMax(out, __float_as_uint(fmaxf(fmaxf(wm[0], wm[1]), fmaxf(wm[2], wm[3]))));
}

// fake-quant to integer codes, stored as bf16 bit patterns (exact for |q|<=255)
__global__ void quant_bf16(const float4* __restrict__ x, ushort4* __restrict__ q4,
                           int n4, const unsigned* __restrict__ scal, int which,
                           float qmax) {
  float s = __uint_as_float(scal[which]) / qmax;
  for (int i = blockIdx.x * blockDim.x + threadIdx.x; i < n4; i += gridDim.x * blockDim.x) {
    float4 v = x[i];
    float a0 = fminf(fmaxf(rintf(v.x / s), -qmax), qmax);
    float a1 = fminf(fmaxf(rintf(v.y / s), -qmax), qmax);
    float a2 = fminf(fmaxf(rintf(v.z / s), -qmax), qmax);
    float a3 = fminf(fmaxf(rintf(v.w / s), -qmax), qmax);
    ushort4 o;
    o.x = (ushort)(__float_as_uint(a0) >> 16);
    o.y = (ushort)(__float_as_uint(a1) >> 16);
    o.z = (ushort)(__float_as_uint(a2) >> 16);
    o.w = (ushort)(__float_as_uint(a3) >> 16);
    q4[i] = o;
  }
}

// GEMM: C[m,n] = sum_k A[m,k]*B[n,k]  (A = qx codes, B = qw codes, both K-major)
// PREQ=true : A read as bf16 codes from ws via global_load_lds
// PREQ=false: A staged from fp32 x with inline quantization (small-ws fallback)
template <bool PREQ>
__global__ __launch_bounds__(256, 3) void gemm_bt(
    const ushort* __restrict__ Aq, const float* __restrict__ Xf,
    const ushort* __restrict__ Bq, const float* __restrict__ bias,
    float* __restrict__ Out, unsigned* __restrict__ scal,
    int M, int N, int K) {
  __shared__ ushort sA[BM * BK];
  __shared__ ushort sB[BN * BK];
  __shared__ float wred[4];

  const int t = threadIdx.x;
  const int lane = t & 63, wave = t >> 6;
  const int wm = wave >> 1, wn = wave & 1;
  const int quad = lane >> 4, l16 = lane & 15;
  const int bm = blockIdx.y * BM, bn = blockIdx.x * BN;

  const float s_in = __uint_as_float(scal[0]) / 127.0f;
  const float s_w = __uint_as_float(scal[1]) / 7.0f;
  const float s_b = s_in * s_w;

  f32x4 acc[4][4] = {};

  for (int k0 = 0; k0 < K; k0 += BK) {
#pragma unroll
    for (int j = 0; j < 4; ++j) {
      const int e = (j * 256 + t) * 8;   // flat bf16 element index in the tile
      const int r = e >> 6;              // row in tile (BK=64 elems/row)
      const int c = e & 63;              // col in tile (multiple of 8)
      async_copy16(Bq + (bn + r) * K + k0 + c, (char*)sB + e * 2);
      if (PREQ) {
        async_copy16(Aq + (bm + r) * K + k0 + c, (char*)sA + e * 2);
      } else {
        const float4* src = (const float4*)(Xf + (size_t)(bm + r) * K + k0 + c);
        float4 v0 = src[0], v1 = src[1];
        float vv[8] = {v0.x, v0.y, v0.z, v0.w, v1.x, v1.y, v1.z, v1.w};
        unsigned p[4];
#pragma unroll
        for (int h = 0; h < 4; ++h) {
          float q0 = fminf(fmaxf(rintf(vv[2 * h] / s_in), -127.f), 127.f);
          float q1 = fminf(fmaxf(rintf(vv[2 * h + 1] / s_in), -127.f), 127.f);
          p[h] = (__float_as_uint(q0) >> 16) | (__float_as_uint(q1) & 0xffff0000u);
        }
        uint4 u = {p[0], p[1], p[2], p[3]};
        *(uint4*)(sA + e) = u;
      }
    }
    __syncthreads();
#pragma unroll
    for (int kk = 0; kk < BK; kk += 32) {
      bf16x8 af[4], bfr[4];
#pragma unroll
      for (int mt = 0; mt < 4; ++mt)
        af[mt] = *(const bf16x8*)&sA[(wm * 64 + mt * 16 + l16) * BK + kk + quad * 8];
#pragma unroll
      for (int nt = 0; nt < 4; ++nt)
        bfr[nt] = *(const bf16x8*)&sB[(wn * 64 + nt * 16 + l16) * BK + kk + quad * 8];
#pragma unroll
      for (int mt = 0; mt < 4; ++mt)
#pragma unroll
        for (int nt = 0; nt < 4; ++nt)
          acc[mt][nt] = __builtin_amdgcn_mfma_f32_16x16x32_bf16(af[mt], bfr[nt], acc[mt][nt], 0, 0, 0);
    }
    __syncthreads();
  }

  // epilogue: t = acc + round(b/s_b); store t (integer-valued fp32); max|t|
  float bi[4];
#pragma unroll
  for (int nt = 0; nt < 4; ++nt) {
    int n = bn + wn * 64 + nt * 16 + l16;
    float q = rintf(bias[n] / s_b);
    bi[nt] = fminf(fmaxf(q, -2147483648.f), 2147483648.f);
  }
  float lmax = 0.f;
#pragma unroll
  for (int mt = 0; mt < 4; ++mt) {
#pragma unroll
    for (int r = 0; r < 4; ++r) {
      int m = bm + wm * 64 + mt * 16 + quad * 4 + r;
      float* orow = Out + (size_t)m * N + bn + wn * 64 + l16;
#pragma unroll
      for (int nt = 0; nt < 4; ++nt) {
        float tv = acc[mt][nt][r] + bi[nt];
        orow[nt * 16] = tv;
        lmax = fmaxf(lmax, fabsf(tv));
      }
    }
  }
  lmax = wave_max64(lmax);
  if (lane == 0) wred[wave] = lmax;
  __syncthreads();
  if (t == 0)
    atomicMax(&scal[2], __float_as_uint(fmaxf(fmaxf(wred[0], wred[1]), fmaxf(wred[2], wred[3]))));
}

__global__ void finalize4(float4* __restrict__ out, int n4, const unsigned* __restrict__ scal) {
  const float s_in = __uint_as_float(scal[0]) / 127.0f;
  const float s_w = __uint_as_float(scal[1]) / 7.0f;
  const float s_b = s_in * s_w;
  const float s_out = (s_b * __uint_as_float(scal[2])) / 127.0f;
  for (int i = blockIdx.x * blockDim.x + threadIdx.x; i < n4; i += gridDim.x * blockDim.x) {
    float4 v = out[i];
    float y;
    y = s_b * v.x; v.x = fminf(fmaxf(rintf(y / s_out), -127.f), 127.f) * s_out;
    y = s_b * v.y; v.y = fminf(fmaxf(rintf(y / s_out), -127.f), 127.f) * s_out;
    y = s_b * v.z; v.z = fminf(fmaxf(rintf(y / s_out), -127.f), 127.f) * s_out;
    y = s_b * v.w; v.w = fminf(fmaxf(rintf(y / s_out), -127.f), 127.f) * s_out;
    out[i] = v;
  }
}

extern "C" void kernel_launch(void* const* d_in, const int* in_sizes, int n_in,
                              void* d_out, int out_size, void* d_ws, size_t ws_size,
                              hipStream_t stream) {
  const float* x = (const float*)d_in[0];
  const float* W = (const float*)d_in[1];
  const float* b = (const float*)d_in[2];
  float* out = (float*)d_out;

  const int N = in_sizes[2];       // 4096 (H)
  const int K = in_sizes[1] / N;   // 4096 (D)
  const int M = in_sizes[0] / K;   // 16384 (tokens)

  unsigned* scal = (unsigned*)d_ws;
  const size_t OFF = 4096;
  const size_t need_pre = OFF + (size_t)2 * M * K + (size_t)2 * N * K;
  const bool preq = ws_size >= need_pre;  // constant across calls -> graph-safe
  ushort* xq = nullptr;
  ushort* wq;
  if (preq) {
    xq = (ushort*)((char*)d_ws + OFF);
    wq = xq + (size_t)M * K;
  } else {
    wq = (ushort*)((char*)d_ws + OFF);
  }

  const int n4x = (M / 4) * K;
  const int n4w = (N / 4) * K;

  init_scal<<<1, 64, 0, stream>>>(scal);
  maxabs4<<<4096, 256, 0, stream>>>((const float4*)x, n4x, scal + 0);
  maxabs4<<<1024, 256, 0, stream>>>((const float4*)W, n4w, scal + 1);
  quant_bf16<<<4096, 256, 0, stream>>>((const float4*)W, (ushort4*)wq, n4w, scal, 1, 7.0f);
  if (preq)
    quant_bf16<<<8192, 256, 0, stream>>>((const float4*)x, (ushort4*)xq, n4x, scal, 0, 127.0f);

  dim3 grid(N / BN, M / BM);
  if (preq)
    gemm_bt<true><<<grid, 256, 0, stream>>>(xq, x, wq, b, out, scal, M, N, K);
  else
    gemm_bt<false><<<grid, 256, 0, stream>>>(xq, x, wq, b, out, scal, M, N, K);

  finalize4<<<8192, 256, 0, stream>>>((float4*)out, (int)((size_t)M * N / 4), scal);
}

// Round 2
// 879.912 us; speedup vs baseline: 1.4489x; 1.4489x over previous
//
#include <hip/hip_runtime.h>
#include <stdint.h>

// ---------------------------------------------------------------------------
// QuantLinearNet: y = fq8( fq8(x) @ fq4(W).T + bq )
// Round 2: integer codes fit int8 -> v_mfma_i32_16x16x64_i8 (exact i32 acc,
// 2x K per MFMA, half the staging bytes of bf16). XOR bank swizzle on the
// LDS tiles. All per-element divides replaced by reciprocal-multiplies.
// ---------------------------------------------------------------------------

typedef __attribute__((ext_vector_type(4))) int i32x4;

#define BM 128
#define BN 128
#define BKB 128  // K-bytes (= i8 elements) per tile

__device__ __forceinline__ void async_copy16(const void* g, void* l) {
  __builtin_amdgcn_global_load_lds((const __attribute__((address_space(1))) void*)g,
                                   (__attribute__((address_space(3))) void*)l,
                                   16, 0, 0);
}

__device__ __forceinline__ float wave_max64(float v) {
#pragma unroll
  for (int off = 32; off > 0; off >>= 1) v = fmaxf(v, __shfl_xor(v, off, 64));
  return v;
}

__global__ void init_scal(unsigned* s) {
  if (threadIdx.x < 4) s[threadIdx.x] = 0u;
}

__global__ void maxabs4(const float4* __restrict__ x, int n4, unsigned* __restrict__ out) {
  float m = 0.f;
  for (int i = blockIdx.x * blockDim.x + threadIdx.x; i < n4; i += gridDim.x * blockDim.x) {
    float4 v = x[i];
    m = fmaxf(fmaxf(fabsf(v.x), fabsf(v.y)), fmaxf(fmaxf(fabsf(v.z), fabsf(v.w)), m));
  }
  m = wave_max64(m);
  __shared__ float wm[4];
  if ((threadIdx.x & 63) == 0) wm[threadIdx.x >> 6] = m;
  __syncthreads();
  if (threadIdx.x == 0)
    atomicMax(out, __float_as_uint(fmaxf(fmaxf(wm[0], wm[1]), fmaxf(wm[2], wm[3]))));
}

// fake-quant fp32 -> int8 codes (two's-complement bytes)
__global__ void quant_i8(const float4* __restrict__ x, uchar4* __restrict__ q,
                         int n4, const unsigned* __restrict__ scal, int which,
                         float qmax) {
  const float inv = qmax / __uint_as_float(scal[which]);  // 1/s, one divide/thread
  for (int i = blockIdx.x * blockDim.x + threadIdx.x; i < n4; i += gridDim.x * blockDim.x) {
    float4 v = x[i];
    int a0 = (int)fminf(fmaxf(rintf(v.x * inv), -qmax), qmax);
    int a1 = (int)fminf(fmaxf(rintf(v.y * inv), -qmax), qmax);
    int a2 = (int)fminf(fmaxf(rintf(v.z * inv), -qmax), qmax);
    int a3 = (int)fminf(fmaxf(rintf(v.w * inv), -qmax), qmax);
    uchar4 o;
    o.x = (unsigned char)a0; o.y = (unsigned char)a1;
    o.z = (unsigned char)a2; o.w = (unsigned char)a3;
    q[i] = o;
  }
}

// C[m,n] = sum_k A[m,k]*B[n,k], A/B int8 codes, K-major.
// LDS tiles use a 16B-chunk XOR swizzle: chunk cc of row r lives at position
// cc ^ (r&7) -> quad's 16 lanes spread over all 32 banks (2/bank = free).
__global__ __launch_bounds__(256, 3) void gemm_i8(
    const uint8_t* __restrict__ Aq, const uint8_t* __restrict__ Bq,
    const float* __restrict__ bias, float* __restrict__ Out,
    unsigned* __restrict__ scal, int M, int N, int K) {
  __shared__ uint8_t sA[BM * BKB];
  __shared__ uint8_t sB[BN * BKB];
  __shared__ float wred[4];

  const int t = threadIdx.x;
  const int lane = t & 63, wave = t >> 6;
  const int wm = wave >> 1, wn = wave & 1;
  const int quad = lane >> 4, l16 = lane & 15;
  const int bm = blockIdx.y * BM, bn = blockIdx.x * BN;

  i32x4 acc[4][4] = {};

  for (int k0 = 0; k0 < K; k0 += BKB) {
#pragma unroll
    for (int j = 0; j < 4; ++j) {
      const int id = j * 256 + t;        // 16B chunk id in tile (1024 total)
      const int r = id >> 3;             // row (8 chunks/row)
      const int cc = id & 7;             // LDS chunk position in row
      const int gc = (cc ^ (r & 7)) << 4;  // swizzled global byte offset
      async_copy16(Aq + (size_t)(bm + r) * K + k0 + gc, sA + id * 16);
      async_copy16(Bq + (size_t)(bn + r) * K + k0 + gc, sB + id * 16);
    }
    __syncthreads();
#pragma unroll
    for (int kk = 0; kk < 2; ++kk) {  // two K=64 steps per tile
      i32x4 af[4], bf[4];
#pragma unroll
      for (int mt = 0; mt < 4; ++mt) {
        const int row = wm * 64 + mt * 16 + l16;
        const int p = (quad + kk * 4) ^ (row & 7);
        af[mt] = *(const i32x4*)&sA[row * BKB + p * 16];
      }
#pragma unroll
      for (int nt = 0; nt < 4; ++nt) {
        const int row = wn * 64 + nt * 16 + l16;
        const int p = (quad + kk * 4) ^ (row & 7);
        bf[nt] = *(const i32x4*)&sB[row * BKB + p * 16];
      }
#pragma unroll
      for (int mt = 0; mt < 4; ++mt)
#pragma unroll
        for (int nt = 0; nt < 4; ++nt)
          acc[mt][nt] = __builtin_amdgcn_mfma_i32_16x16x64_i8(af[mt], bf[nt], acc[mt][nt], 0, 0, 0);
    }
    __syncthreads();
  }

  // epilogue: t = acc + round(b/s_b); store integer-valued fp32 t; max|t|
  const float s_in = __uint_as_float(scal[0]) / 127.0f;
  const float s_w = __uint_as_float(scal[1]) / 7.0f;
  const float s_b = s_in * s_w;
  float bi[4];
#pragma unroll
  for (int nt = 0; nt < 4; ++nt) {
    const int n = bn + wn * 64 + nt * 16 + l16;
    bi[nt] = rintf(bias[n] / s_b);  // 4 divides/thread, epilogue-only
  }
  float lmax = 0.f;
#pragma unroll
  for (int mt = 0; mt < 4; ++mt) {
#pragma unroll
    for (int r = 0; r < 4; ++r) {
      const int m = bm + wm * 64 + mt * 16 + quad * 4 + r;
      float* orow = Out + (size_t)m * N + bn + wn * 64 + l16;
#pragma unroll
      for (int nt = 0; nt < 4; ++nt) {
        float tv = (float)acc[mt][nt][r] + bi[nt];
        orow[nt * 16] = tv;
        lmax = fmaxf(lmax, fabsf(tv));
      }
    }
  }
  lmax = wave_max64(lmax);
  if (lane == 0) wred[wave] = lmax;
  __syncthreads();
  if (t == 0)
    atomicMax(&scal[2], __float_as_uint(fmaxf(fmaxf(wred[0], wred[1]), fmaxf(wred[2], wred[3]))));
}

__global__ void finalize4(float4* __restrict__ out, int n4, const unsigned* __restrict__ scal) {
  const float s_in = __uint_as_float(scal[0]) / 127.0f;
  const float s_w = __uint_as_float(scal[1]) / 7.0f;
  const float s_b = s_in * s_w;
  const float maxt = __uint_as_float(scal[2]);
  const float s_out = (s_b * maxt) / 127.0f;
  const float inv = 127.0f / maxt;  // rint(t*inv) == rint(y/s_out) to ~1ulp
  for (int i = blockIdx.x * blockDim.x + threadIdx.x; i < n4; i += gridDim.x * blockDim.x) {
    float4 v = out[i];
    v.x = fminf(fmaxf(rintf(v.x * inv), -127.f), 127.f) * s_out;
    v.y = fminf(fmaxf(rintf(v.y * inv), -127.f), 127.f) * s_out;
    v.z = fminf(fmaxf(rintf(v.z * inv), -127.f), 127.f) * s_out;
    v.w = fminf(fmaxf(rintf(v.w * inv), -127.f), 127.f) * s_out;
    out[i] = v;
  }
}

extern "C" void kernel_launch(void* const* d_in, const int* in_sizes, int n_in,
                              void* d_out, int out_size, void* d_ws, size_t ws_size,
                              hipStream_t stream) {
  const float* x = (const float*)d_in[0];
  const float* W = (const float*)d_in[1];
  const float* b = (const float*)d_in[2];
  float* out = (float*)d_out;

  const int N = in_sizes[2];       // 4096 (H)
  const int K = in_sizes[1] / N;   // 4096 (D)
  const int M = in_sizes[0] / K;   // 16384 (tokens)

  unsigned* scal = (unsigned*)d_ws;
  const size_t OFF = 4096;
  uint8_t* xq = (uint8_t*)d_ws + OFF;            // M*K bytes
  uint8_t* wq = xq + (size_t)M * K;              // N*K bytes
  // need = 4K + 80 MB; ws proven >= 160 MB in round 1.

  const int n4x = (M / 4) * K;
  const int n4w = (N / 4) * K;

  init_scal<<<1, 64, 0, stream>>>(scal);
  maxabs4<<<4096, 256, 0, stream>>>((const float4*)x, n4x, scal + 0);
  maxabs4<<<1024, 256, 0, stream>>>((const float4*)W, n4w, scal + 1);
  quant_i8<<<4096, 256, 0, stream>>>((const float4*)W, (uchar4*)wq, n4w, scal, 1, 7.0f);
  quant_i8<<<8192, 256, 0, stream>>>((const float4*)x, (uchar4*)xq, n4x, scal, 0, 127.0f);

  dim3 grid(N / BN, M / BM);
  gemm_i8<<<grid, 256, 0, stream>>>(xq, wq, b, out, scal, M, N, K);

  finalize4<<<8192, 256, 0, stream>>>((float4*)out, (int)((size_t)M * N / 4), scal);
}

// Round 3
// 873.850 us; speedup vs baseline: 1.4589x; 1.0069x over previous
//
#include <hip/hip_runtime.h>
#include <stdint.h>

// ---------------------------------------------------------------------------
// QuantLinearNet: y = fq8( fq8(x) @ fq4(W).T + bq )
// Round 3: i8 MFMA GEMM kept (0 bank conflicts, 45% of i8 ceiling).
// Fuse elementwise passes (7 launches -> 5 nodes incl. memset), vectorize
// quant stores to uint4, bump GEMM to 4 blocks/CU.
// ---------------------------------------------------------------------------

typedef __attribute__((ext_vector_type(4))) int i32x4;

#define BM 128
#define BN 128
#define BKB 128  // K-bytes (= i8 elements) per tile

__device__ __forceinline__ void async_copy16(const void* g, void* l) {
  __builtin_amdgcn_global_load_lds((const __attribute__((address_space(1))) void*)g,
                                   (__attribute__((address_space(3))) void*)l,
                                   16, 0, 0);
}

__device__ __forceinline__ float wave_max64(float v) {
#pragma unroll
  for (int off = 32; off > 0; off >>= 1) v = fmaxf(v, __shfl_xor(v, off, 64));
  return v;
}

__device__ __forceinline__ float max4(float4 v) {
  return fmaxf(fmaxf(fabsf(v.x), fabsf(v.y)), fmaxf(fabsf(v.z), fabsf(v.w)));
}

// blocks [0, WBLK) reduce W, the rest reduce x. One launch, two atomics.
#define WBLK 1024
__global__ void maxabs_both(const float4* __restrict__ x, int n4x,
                            const float4* __restrict__ w, int n4w,
                            unsigned* __restrict__ scal) {
  const bool isW = (int)blockIdx.x < WBLK;
  const float4* __restrict__ p = isW ? w : x;
  const int n4 = isW ? n4w : n4x;
  const int bid = isW ? blockIdx.x : blockIdx.x - WBLK;
  const int nb = isW ? WBLK : gridDim.x - WBLK;
  const int stride = nb * blockDim.x;

  float m0 = 0.f, m1 = 0.f;
  int i = bid * blockDim.x + threadIdx.x;
  for (; i + stride < n4; i += 2 * stride) {
    float4 a = p[i], b = p[i + stride];
    m0 = fmaxf(m0, max4(a));
    m1 = fmaxf(m1, max4(b));
  }
  if (i < n4) m0 = fmaxf(m0, max4(p[i]));
  float m = wave_max64(fmaxf(m0, m1));

  __shared__ float wm[4];
  if ((threadIdx.x & 63) == 0) wm[threadIdx.x >> 6] = m;
  __syncthreads();
  if (threadIdx.x == 0)
    atomicMax(&scal[isW ? 1 : 0],
              __float_as_uint(fmaxf(fmaxf(wm[0], wm[1]), fmaxf(wm[2], wm[3]))));
}

// fake-quant fp32 -> int8 codes; 16 codes/thread/iter (64B read, 16B write).
// blocks [0, WBLK) quantize W (qmax=7), the rest x (qmax=127).
__global__ void quant_both(const float4* __restrict__ x, uint4* __restrict__ xq, int ncx,
                           const float4* __restrict__ w, uint4* __restrict__ wq, int ncw,
                           const unsigned* __restrict__ scal) {
  const bool isW = (int)blockIdx.x < WBLK;
  const float4* __restrict__ src = isW ? w : x;
  uint4* __restrict__ dst = isW ? wq : xq;
  const int nc = isW ? ncw : ncx;
  const int bid = isW ? blockIdx.x : blockIdx.x - WBLK;
  const int nb = isW ? WBLK : gridDim.x - WBLK;
  const float qmax = isW ? 7.f : 127.f;
  const float inv = qmax / __uint_as_float(scal[isW ? 1 : 0]);

  for (int c = bid * blockDim.x + threadIdx.x; c < nc; c += nb * blockDim.x) {
    unsigned uu[4];
#pragma unroll
    for (int h = 0; h < 4; ++h) {
      float4 v = src[c * 4 + h];
      unsigned b0 = (unsigned)(int)fminf(fmaxf(rintf(v.x * inv), -qmax), qmax) & 0xffu;
      unsigned b1 = (unsigned)(int)fminf(fmaxf(rintf(v.y * inv), -qmax), qmax) & 0xffu;
      unsigned b2 = (unsigned)(int)fminf(fmaxf(rintf(v.z * inv), -qmax), qmax) & 0xffu;
      unsigned b3 = (unsigned)(int)fminf(fmaxf(rintf(v.w * inv), -qmax), qmax) & 0xffu;
      uu[h] = b0 | (b1 << 8) | (b2 << 16) | (b3 << 24);
    }
    uint4 u; u.x = uu[0]; u.y = uu[1]; u.z = uu[2]; u.w = uu[3];
    dst[c] = u;
  }
}

// C[m,n] = sum_k A[m,k]*B[n,k], A/B int8 codes, K-major.
// 16B-chunk XOR swizzle on LDS rows -> 0 bank conflicts (verified round 2).
__global__ __launch_bounds__(256, 4) void gemm_i8(
    const uint8_t* __restrict__ Aq, const uint8_t* __restrict__ Bq,
    const float* __restrict__ bias, float* __restrict__ Out,
    unsigned* __restrict__ scal, int M, int N, int K) {
  __shared__ uint8_t sA[BM * BKB];
  __shared__ uint8_t sB[BN * BKB];
  __shared__ float wred[4];

  const int t = threadIdx.x;
  const int lane = t & 63, wave = t >> 6;
  const int wm = wave >> 1, wn = wave & 1;
  const int quad = lane >> 4, l16 = lane & 15;
  const int bm = blockIdx.y * BM, bn = blockIdx.x * BN;

  i32x4 acc[4][4] = {};

  for (int k0 = 0; k0 < K; k0 += BKB) {
#pragma unroll
    for (int j = 0; j < 4; ++j) {
      const int id = j * 256 + t;          // 16B chunk id in tile (1024 total)
      const int r = id >> 3;               // row (8 chunks/row)
      const int cc = id & 7;               // LDS chunk position in row
      const int gc = (cc ^ (r & 7)) << 4;  // swizzled global byte offset
      async_copy16(Aq + (size_t)(bm + r) * K + k0 + gc, sA + id * 16);
      async_copy16(Bq + (size_t)(bn + r) * K + k0 + gc, sB + id * 16);
    }
    __syncthreads();
#pragma unroll
    for (int kk = 0; kk < 2; ++kk) {  // two K=64 steps per tile
      i32x4 af[4], bf[4];
#pragma unroll
      for (int mt = 0; mt < 4; ++mt) {
        const int row = wm * 64 + mt * 16 + l16;
        const int p = (quad + kk * 4) ^ (row & 7);
        af[mt] = *(const i32x4*)&sA[row * BKB + p * 16];
      }
#pragma unroll
      for (int nt = 0; nt < 4; ++nt) {
        const int row = wn * 64 + nt * 16 + l16;
        const int p = (quad + kk * 4) ^ (row & 7);
        bf[nt] = *(const i32x4*)&sB[row * BKB + p * 16];
      }
#pragma unroll
      for (int mt = 0; mt < 4; ++mt)
#pragma unroll
        for (int nt = 0; nt < 4; ++nt)
          acc[mt][nt] = __builtin_amdgcn_mfma_i32_16x16x64_i8(af[mt], bf[nt], acc[mt][nt], 0, 0, 0);
    }
    __syncthreads();
  }

  // epilogue: t = acc + round(b/s_b); store integer-valued fp32 t; max|t|
  const float s_in = __uint_as_float(scal[0]) / 127.0f;
  const float s_w = __uint_as_float(scal[1]) / 7.0f;
  const float s_b = s_in * s_w;
  float bi[4];
#pragma unroll
  for (int nt = 0; nt < 4; ++nt) {
    const int n = bn + wn * 64 + nt * 16 + l16;
    bi[nt] = rintf(bias[n] / s_b);  // 4 divides/thread, epilogue-only
  }
  float lmax = 0.f;
#pragma unroll
  for (int mt = 0; mt < 4; ++mt) {
#pragma unroll
    for (int r = 0; r < 4; ++r) {
      const int m = bm + wm * 64 + mt * 16 + quad * 4 + r;
      float* orow = Out + (size_t)m * N + bn + wn * 64 + l16;
#pragma unroll
      for (int nt = 0; nt < 4; ++nt) {
        float tv = (float)acc[mt][nt][r] + bi[nt];
        orow[nt * 16] = tv;
        lmax = fmaxf(lmax, fabsf(tv));
      }
    }
  }
  lmax = wave_max64(lmax);
  if (lane == 0) wred[wave] = lmax;
  __syncthreads();
  if (t == 0)
    atomicMax(&scal[2], __float_as_uint(fmaxf(fmaxf(wred[0], wred[1]), fmaxf(wred[2], wred[3]))));
}

__global__ void finalize4(float4* __restrict__ out, int n4, const unsigned* __restrict__ scal) {
  const float s_in = __uint_as_float(scal[0]) / 127.0f;
  const float s_w = __uint_as_float(scal[1]) / 7.0f;
  const float s_b = s_in * s_w;
  const float maxt = __uint_as_float(scal[2]);
  const float s_out = (s_b * maxt) / 127.0f;
  const float inv = 127.0f / maxt;
  const int stride = gridDim.x * blockDim.x;
  for (int i = blockIdx.x * blockDim.x + threadIdx.x; i < n4; i += stride) {
    float4 v = out[i];
    v.x = fminf(fmaxf(rintf(v.x * inv), -127.f), 127.f) * s_out;
    v.y = fminf(fmaxf(rintf(v.y * inv), -127.f), 127.f) * s_out;
    v.z = fminf(fmaxf(rintf(v.z * inv), -127.f), 127.f) * s_out;
    v.w = fminf(fmaxf(rintf(v.w * inv), -127.f), 127.f) * s_out;
    out[i] = v;
  }
}

extern "C" void kernel_launch(void* const* d_in, const int* in_sizes, int n_in,
                              void* d_out, int out_size, void* d_ws, size_t ws_size,
                              hipStream_t stream) {
  const float* x = (const float*)d_in[0];
  const float* W = (const float*)d_in[1];
  const float* b = (const float*)d_in[2];
  float* out = (float*)d_out;

  const int N = in_sizes[2];       // 4096 (H)
  const int K = in_sizes[1] / N;   // 4096 (D)
  const int M = in_sizes[0] / K;   // 16384 (tokens)

  unsigned* scal = (unsigned*)d_ws;
  const size_t OFF = 4096;
  uint8_t* xq = (uint8_t*)d_ws + OFF;  // M*K bytes
  uint8_t* wq = xq + (size_t)M * K;    // N*K bytes

  const int n4x = (M / 4) * K;         // x in float4 units
  const int n4w = (N / 4) * K;         // W in float4 units
  const int ncx = n4x / 4;             // x in 16-element chunks
  const int ncw = n4w / 4;             // W in 16-element chunks

  hipMemsetAsync(scal, 0, 16, stream);
  maxabs_both<<<WBLK + 4096, 256, 0, stream>>>((const float4*)x, n4x,
                                               (const float4*)W, n4w, scal);
  quant_both<<<WBLK + 4096, 256, 0, stream>>>((const float4*)x, (uint4*)xq, ncx,
                                              (const float4*)W, (uint4*)wq, ncw, scal);

  dim3 grid(N / BN, M / BM);
  gemm_i8<<<grid, 256, 0, stream>>>(xq, wq, b, out, scal, M, N, K);

  finalize4<<<8192, 256, 0, stream>>>((float4*)out, (int)((size_t)M * N / 4), scal);
}